// Round 5
// baseline (744.708 us; speedup 1.0000x reference)
//
#include <hip/hip_runtime.h>
#include <math.h>

#define B_ 16
#define S_ 1024
#define D_ 512
#define H_ 4
#define INV_TEMP 0.044194173824159216f   // 1/sqrt(512)
#define C_SCALE 0.00390625f              // 2^-8 range guard for fp16 scores
#define NPMAX 32

typedef _Float16 f16;
typedef _Float16 f16x8 __attribute__((ext_vector_type(8)));
typedef _Float16 f16x4 __attribute__((ext_vector_type(4)));
typedef float f32x4 __attribute__((ext_vector_type(4)));

#define AS1(p) ((const __attribute__((address_space(1))) void*)(p))
#define AS3(p) ((__attribute__((address_space(3))) void*)(p))
#define MFMA __builtin_amdgcn_mfma_f32_16x16x32_f16

// ---------------------------------------------------------------------------
__global__ __launch_bounds__(256)
void k_conv(const float* __restrict__ src, f16* __restrict__ dst)
{
    const int i = blockIdx.x * 256 + threadIdx.x;
    const float4 v = ((const float4*)src)[i];
    f16x4 h; h[0] = (f16)v.x; h[1] = (f16)v.y; h[2] = (f16)v.z; h[3] = (f16)v.w;
    ((f16x4*)dst)[i] = h;
}

__global__ __launch_bounds__(256)
void k_zero(float* __restrict__ p)
{
    p[blockIdx.x * 256 + threadIdx.x] = 0.0f;
}

// ---------------------------------------------------------------------------
// m97-style staging/MMA core (proven in round 2)
// ---------------------------------------------------------------------------
__device__ __forceinline__ void stage128x32(const f16* __restrict__ src, int ld,
                                            char* lds0, int t)
{
    const f16* g0 = src + (size_t)(t >> 2) * ld + (t & 3) * 8;
    __builtin_amdgcn_global_load_lds(AS1(g0), AS3(lds0 + t * 16), 16, 0, 0);
    const f16* g1 = g0 + (size_t)64 * ld;
    __builtin_amdgcn_global_load_lds(AS1(g1), AS3(lds0 + 4096 + t * 16), 16, 0, 0);
}

__device__ __forceinline__ void mma_chunk(const char* ldsA, const char* ldsB,
                                          int wm, int wn, int lr, int quad,
                                          f32x4 (*acc)[4])
{
    f16x8 af[4], bf[4];
#pragma unroll
    for (int i = 0; i < 4; ++i)
        af[i] = *(const f16x8*)(ldsA + ((wm * 64 + i * 16 + lr) * 32 + quad * 8) * 2);
#pragma unroll
    for (int j = 0; j < 4; ++j)
        bf[j] = *(const f16x8*)(ldsB + ((wn * 64 + j * 16 + lr) * 32 + quad * 8) * 2);
#pragma unroll
    for (int i = 0; i < 4; ++i)
#pragma unroll
        for (int j = 0; j < 4; ++j)
            acc[i][j] = MFMA(af[i], bf[j], acc[i][j], 0, 0, 0);
}

__device__ __forceinline__ void gemm_core(const f16* A, int ldA, const f16* Bm, int ldB,
                                          int K, char* lds, int t, int wm, int wn,
                                          int lr, int quad, f32x4 (*acc)[4])
{
    for (int k0 = 0; k0 < K; k0 += 32) {
        stage128x32(A + k0, ldA, lds, t);
        stage128x32(Bm + k0, ldB, lds + 8192, t);
        __syncthreads();
        mma_chunk(lds, lds + 8192, wm, wn, lr, quad, acc);
        __syncthreads();
    }
}

// ===========================================================================
// vT = ELU(x @ W^T + b)^T  stored [B][D][S] fp16
// ===========================================================================
__global__ __launch_bounds__(256)
void k_gemm_v(const f16* __restrict__ xh, const f16* __restrict__ Wh,
              const float* __restrict__ bias, f16* __restrict__ vT)
{
    __shared__ __align__(16) char lds[16384];
    const int t = threadIdx.x;
    const int w = t >> 6, lane = t & 63, lr = lane & 15, quad = lane >> 4;
    const int wm = w & 1, wn = w >> 1;
    const int bm = blockIdx.x * 128;
    const int bn = blockIdx.y * 128;
    f32x4 acc[4][4] = {};
    gemm_core(xh + (size_t)bm * D_, D_, Wh + (size_t)bn * D_, D_, D_,
              lds, t, wm, wn, lr, quad, acc);
#pragma unroll
    for (int j = 0; j < 4; ++j) {
        const int e = bn + wn * 64 + j * 16 + lr;
        const float be = bias[e];
#pragma unroll
        for (int i = 0; i < 4; ++i) {
            const int m = bm + wm * 64 + i * 16 + quad * 4;
            const int batch = m >> 10, s = m & 1023;
            f16x4 hv;
#pragma unroll
            for (int r = 0; r < 4; ++r) {
                float z = acc[i][j][r] + be;
                z = (z > 0.0f) ? z : (expf(z) - 1.0f);
                hv[r] = (f16)z;
            }
            *(f16x4*)(vT + ((size_t)batch * D_ + e) * S_ + s) = hv;
        }
    }
}

// ===========================================================================
// k_scores: only upper-triangular tiles (kt >= qt). M = keys, N = queries.
// Epilogue: fp16 store (x C_SCALE) + fp32 ss accumulation -> ssbuf atomics.
// grid (36, B); 36 = triangular tile count per batch.
// ===========================================================================
__global__ __launch_bounds__(256)
void k_scores(const f16* __restrict__ xh, const int* __restrict__ etype,
              f16* __restrict__ sh, float* __restrict__ ssbuf)
{
    __shared__ __align__(16) char lds[16384];
    __shared__ float ssq[128];
    const int t = threadIdx.x;
    const int w = t >> 6, lane = t & 63, lr = lane & 15, quad = lane >> 4;
    const int wm = w & 1, wn = w >> 1;
    const int b = blockIdx.y;
    // triangular decode: blockIdx.x -> (qt, kt) with kt >= qt
    int ii = blockIdx.x, qt = 0;
    while (ii >= 8 - qt) { ii -= 8 - qt; ++qt; }
    const int kt = qt + ii;
    const int bk = kt * 128;   // keys (M)
    const int bq = qt * 128;   // queries (N)

    if (t < 128) ssq[t] = 0.0f;
    const f16* xb = xh + (size_t)b * S_ * D_;
    f32x4 acc[4][4] = {};
    gemm_core(xb + (size_t)bk * D_, D_, xb + (size_t)bq * D_, D_, D_,
              lds, t, wm, wn, lr, quad, acc);

    float ssl[4] = {};
#pragma unroll
    for (int i = 0; i < 4; ++i) {
        const int k4 = bk + wm * 64 + i * 16 + quad * 4;
        const int4 et = *(const int4*)(etype + b * S_ + k4);
        const int ev[4] = {et.x, et.y, et.z, et.w};
#pragma unroll
        for (int j = 0; j < 4; ++j) {
            const int q = bq + wn * 64 + j * 16 + lr;
            f16x4 hv;
#pragma unroll
            for (int r = 0; r < 4; ++r) {
                const bool keep = ((k4 + r) > q) || (ev[r] == 0);
                float sv = keep ? acc[i][j][r] * INV_TEMP : 0.0f;
                ssl[j] += sv * sv;
                hv[r] = (f16)(sv * C_SCALE);
            }
            *(f16x4*)(sh + ((size_t)b * S_ + q) * S_ + k4) = hv;
        }
    }
    // reduce ss over quad (lane bits 4,5), then combine waves via LDS atomics
#pragma unroll
    for (int j = 0; j < 4; ++j) {
        float v = ssl[j];
        v += __shfl_xor(v, 16); v += __shfl_xor(v, 32);
        if (quad == 0) atomicAdd(&ssq[wn * 64 + j * 16 + lr], v);
    }
    __syncthreads();
    if (t < 128) atomicAdd(&ssbuf[b * S_ + bq + t], ssq[t]);
}

// ===========================================================================
// pad handling: scan (once), strip (per head), invq (per head)
// ===========================================================================
__global__ __launch_bounds__(256)
void k_padscan(const int* __restrict__ etype, int* __restrict__ padcnt,
               int* __restrict__ padpos)
{
    const int b = blockIdx.x, t = threadIdx.x;
    if (t == 0) padcnt[b] = 0;
    __syncthreads();
#pragma unroll
    for (int r = 0; r < 4; ++r) {
        const int k = t * 4 + r;
        if (etype[b * S_ + k] == 0) {
            const int s = atomicAdd(&padcnt[b], 1);
            if (s < NPMAX) padpos[b * NPMAX + s] = k;
        }
    }
}

__global__ __launch_bounds__(256)
void k_padstrip(const f16* __restrict__ xh, const int* __restrict__ padcnt,
                const int* __restrict__ padpos, float* __restrict__ padsc,
                float* __restrict__ ssbuf)
{
    const int sl = blockIdx.x, b = blockIdx.y, t = threadIdx.x;
    const int np = min(padcnt[b], NPMAX);
    if (sl >= np) return;
    const int p = padpos[b * NPMAX + sl];
    __shared__ __align__(16) f16 xp[D_];
    const f16* xb = xh + (size_t)b * S_ * D_;
    if (t < 64) *(f16x8*)(xp + t * 8) = *(const f16x8*)(xb + (size_t)p * D_ + t * 8);
    __syncthreads();
    const int qlim = ((p >> 7) + 1) << 7;   // strip counted only for q >= qlim
#pragma unroll
    for (int qq = 0; qq < 4; ++qq) {
        const int q = qq * 256 + t;
        float d = 0.0f;
        for (int c = 0; c < 64; ++c) {
            const f16x8 a = *(const f16x8*)(xb + (size_t)q * D_ + c * 8);
            const f16x8 bb = *(const f16x8*)(xp + c * 8);
#pragma unroll
            for (int r = 0; r < 8; ++r) d += (float)a[r] * (float)bb[r];
        }
        const float sp = d * INV_TEMP;
        padsc[((size_t)b * NPMAX + sl) * S_ + q] = sp * C_SCALE;
        if (q >= qlim) atomicAdd(&ssbuf[b * S_ + q], sp * sp);
    }
}

__global__ __launch_bounds__(256)
void k_invq(const float* __restrict__ ssbuf, float* __restrict__ invq)
{
    const int i = blockIdx.x * 256 + threadIdx.x;
    invq[i] = 1.0f / (C_SCALE * fmaxf(sqrtf(ssbuf[i]), 1e-5f));
}

// ===========================================================================
// k_out: x_new = inv * (Sc @ v) + pad fixup. M = e (A=vT), N = q (B=sh).
// K-loop starts at the q-tile diagonal (dead tiles skipped / unwritten).
// ===========================================================================
__global__ __launch_bounds__(256)
void k_out(const f16* __restrict__ vT, const f16* __restrict__ sh,
           const float* __restrict__ invq, const int* __restrict__ padcnt,
           const int* __restrict__ padpos, const float* __restrict__ padsc,
           f16* __restrict__ xnext, float* __restrict__ out, const int accum)
{
    __shared__ __align__(16) char lds[16384];
    const int t = threadIdx.x;
    const int w = t >> 6, lane = t & 63, lr = lane & 15, quad = lane >> 4;
    const int wm = w & 1, wn = w >> 1;
    const int b = blockIdx.z;
    const int be = blockIdx.x * 128;
    const int bq = blockIdx.y * 128;
    f32x4 acc[4][4] = {};
    gemm_core(vT + ((size_t)b * D_ + be) * S_ + bq,
              S_, sh + ((size_t)b * S_ + bq) * S_ + bq, S_, S_ - bq,
              lds, t, wm, wn, lr, quad, acc);

    // pad fixup for columns p < bq (skipped region)
    const int np = min(padcnt[b], NPMAX);
    for (int sl = 0; sl < np; ++sl) {
        const int p = padpos[b * NPMAX + sl];
        if (p >= bq) continue;
        float sp[4];
#pragma unroll
        for (int j = 0; j < 4; ++j)
            sp[j] = padsc[((size_t)b * NPMAX + sl) * S_ + bq + wn * 64 + j * 16 + lr];
#pragma unroll
        for (int i = 0; i < 4; ++i) {
#pragma unroll
            for (int r = 0; r < 4; ++r) {
                const int e = be + wm * 64 + i * 16 + quad * 4 + r;
                const float vv = (float)vT[((size_t)b * D_ + e) * S_ + p];
#pragma unroll
                for (int j = 0; j < 4; ++j) acc[i][j][r] += sp[j] * vv;
            }
        }
    }

#pragma unroll
    for (int j = 0; j < 4; ++j) {
        const int q = bq + wn * 64 + j * 16 + lr;
        const float inv = invq[b * S_ + q];
#pragma unroll
        for (int i = 0; i < 4; ++i) {
            const int e4 = be + wm * 64 + i * 16 + quad * 4;
            const size_t o = ((size_t)b * S_ + q) * D_ + e4;
            f32x4 val;
            f16x4 hx;
#pragma unroll
            for (int r = 0; r < 4; ++r) {
                val[r] = acc[i][j][r] * inv;
                hx[r] = (f16)val[r];
            }
            if (accum) { const f32x4 old = *(const f32x4*)(out + o); val = val + old; }
            *(f32x4*)(out + o) = val;
            *(f16x4*)(xnext + o) = hx;
        }
    }
}

// ---------------------------------------------------------------------------
// Workspace (bytes):
//   X0 @0 (16M), X1 @16M, vT @32M, Wh @48M (2M),
//   ssbuf @50M (64K), invq @50M+64K (64K), padcnt @50M+128K (4K),
//   padpos @50M+132K (4K), padsc @51M (2M), sh @53M (32M)  -> 85M total
// ---------------------------------------------------------------------------
extern "C" void kernel_launch(void* const* d_in, const int* in_sizes, int n_in,
                              void* d_out, int out_size, void* d_ws, size_t ws_size,
                              hipStream_t stream) {
    const float* x0    = (const float*)d_in[0];
    const int*   etype = (const int*)d_in[2];
    const float* W     = (const float*)d_in[3];
    const float* bias  = (const float*)d_in[4];
    float* out = (float*)d_out;

    char* ws = (char*)d_ws;
    const size_t MB = 1u << 20;
    f16*   X0    = (f16*)(ws);
    f16*   X1    = (f16*)(ws + 16 * MB);
    f16*   vT    = (f16*)(ws + 32 * MB);
    f16*   Wh    = (f16*)(ws + 48 * MB);
    float* ssbuf = (float*)(ws + 50 * MB);
    float* invq  = (float*)(ws + 50 * MB + 65536);
    int*   padcnt= (int*)(ws + 50 * MB + 131072);
    int*   padpos= (int*)(ws + 50 * MB + 135168);
    float* padsc = (float*)(ws + 51 * MB);
    f16*   sh    = (f16*)(ws + 53 * MB);

    k_conv<<<8192, 256, 0, stream>>>(x0, X0);
    k_conv<<<1024, 256, 0, stream>>>(W, Wh);
    k_padscan<<<B_, 256, 0, stream>>>(etype, padcnt, padpos);

    const dim3 gridV(128, 4);
    const dim3 gridS(36, B_);
    const dim3 gridP(NPMAX, B_);
    const dim3 gridO(4, 8, B_);
    for (int h = 0; h < H_; ++h) {
        f16* Xc = (h & 1) ? X1 : X0;
        f16* Xn = (h & 1) ? X0 : X1;
        k_zero    <<<64, 256, 0, stream>>>(ssbuf);
        k_gemm_v  <<<gridV, 256, 0, stream>>>(Xc, Wh + (size_t)h * D_ * D_,
                                              bias + (size_t)h * D_, vT);
        k_scores  <<<gridS, 256, 0, stream>>>(Xc, etype, sh, ssbuf);
        k_padstrip<<<gridP, 256, 0, stream>>>(Xc, padcnt, padpos, padsc, ssbuf);
        k_invq    <<<64, 256, 0, stream>>>(ssbuf, invq);
        k_out     <<<gridO, 256, 0, stream>>>(vT, sh, invq, padcnt, padpos, padsc,
                                              Xn, out, h > 0);
    }
}

// Round 6
// 636.949 us; speedup vs baseline: 1.1692x; 1.1692x over previous
//
#include <hip/hip_runtime.h>
#include <math.h>

#define B_ 16
#define S_ 1024
#define D_ 512
#define H_ 4
#define INV_TEMP 0.044194173824159216f   // 1/sqrt(512)
#define C_SCALE 0.00390625f              // 2^-8 range guard for fp16 scores
#define NPMAX 32

typedef _Float16 f16;
typedef _Float16 f16x8 __attribute__((ext_vector_type(8)));
typedef _Float16 f16x4 __attribute__((ext_vector_type(4)));
typedef float f32x4 __attribute__((ext_vector_type(4)));

#define AS1(p) ((const __attribute__((address_space(1))) void*)(p))
#define AS3(p) ((__attribute__((address_space(3))) void*)(p))
#define MFMA __builtin_amdgcn_mfma_f32_16x16x32_f16

// ---------------------------------------------------------------------------
__global__ __launch_bounds__(256)
void k_conv(const float* __restrict__ src, f16* __restrict__ dst)
{
    const int i = blockIdx.x * 256 + threadIdx.x;
    const float4 v = ((const float4*)src)[i];
    f16x4 h; h[0] = (f16)v.x; h[1] = (f16)v.y; h[2] = (f16)v.z; h[3] = (f16)v.w;
    ((f16x4*)dst)[i] = h;
}

// ---------------------------------------------------------------------------
// m97-style staging/MMA core (proven in round 2)
// ---------------------------------------------------------------------------
__device__ __forceinline__ void stage128x32(const f16* __restrict__ src, int ld,
                                            char* lds0, int t)
{
    const f16* g0 = src + (size_t)(t >> 2) * ld + (t & 3) * 8;
    __builtin_amdgcn_global_load_lds(AS1(g0), AS3(lds0 + t * 16), 16, 0, 0);
    const f16* g1 = g0 + (size_t)64 * ld;
    __builtin_amdgcn_global_load_lds(AS1(g1), AS3(lds0 + 4096 + t * 16), 16, 0, 0);
}

__device__ __forceinline__ void mma_chunk(const char* ldsA, const char* ldsB,
                                          int wm, int wn, int lr, int quad,
                                          f32x4 (*acc)[4])
{
    f16x8 af[4], bf[4];
#pragma unroll
    for (int i = 0; i < 4; ++i)
        af[i] = *(const f16x8*)(ldsA + ((wm * 64 + i * 16 + lr) * 32 + quad * 8) * 2);
#pragma unroll
    for (int j = 0; j < 4; ++j)
        bf[j] = *(const f16x8*)(ldsB + ((wn * 64 + j * 16 + lr) * 32 + quad * 8) * 2);
#pragma unroll
    for (int i = 0; i < 4; ++i)
#pragma unroll
        for (int j = 0; j < 4; ++j)
            acc[i][j] = MFMA(af[i], bf[j], acc[i][j], 0, 0, 0);
}

__device__ __forceinline__ void gemm_core(const f16* A, int ldA, const f16* Bm, int ldB,
                                          int K, char* lds, int t, int wm, int wn,
                                          int lr, int quad, f32x4 (*acc)[4])
{
    for (int k0 = 0; k0 < K; k0 += 32) {
        stage128x32(A + k0, ldA, lds, t);
        stage128x32(Bm + k0, ldB, lds + 8192, t);
        __syncthreads();
        mma_chunk(lds, lds + 8192, wm, wn, lr, quad, acc);
        __syncthreads();
    }
}

// ===========================================================================
// vT = ELU(x @ W^T + b)^T  stored [B][D][S] fp16.
// Block (0,0) also zeroes ssbuf for the downstream atomics (stream-ordered).
// ===========================================================================
__global__ __launch_bounds__(256)
void k_gemm_v(const f16* __restrict__ xh, const f16* __restrict__ Wh,
              const float* __restrict__ bias, f16* __restrict__ vT,
              float* __restrict__ ssbuf)
{
    __shared__ __align__(16) char lds[16384];
    const int t = threadIdx.x;
    if (blockIdx.x == 0 && blockIdx.y == 0) {
        const float4 z = {0.0f, 0.0f, 0.0f, 0.0f};
#pragma unroll
        for (int i = 0; i < 16; ++i) ((float4*)ssbuf)[i * 256 + t] = z;
    }
    const int w = t >> 6, lane = t & 63, lr = lane & 15, quad = lane >> 4;
    const int wm = w & 1, wn = w >> 1;
    const int bm = blockIdx.x * 128;
    const int bn = blockIdx.y * 128;
    f32x4 acc[4][4] = {};
    gemm_core(xh + (size_t)bm * D_, D_, Wh + (size_t)bn * D_, D_, D_,
              lds, t, wm, wn, lr, quad, acc);
#pragma unroll
    for (int j = 0; j < 4; ++j) {
        const int e = bn + wn * 64 + j * 16 + lr;
        const float be = bias[e];
#pragma unroll
        for (int i = 0; i < 4; ++i) {
            const int m = bm + wm * 64 + i * 16 + quad * 4;
            const int batch = m >> 10, s = m & 1023;
            f16x4 hv;
#pragma unroll
            for (int r = 0; r < 4; ++r) {
                float z = acc[i][j][r] + be;
                z = (z > 0.0f) ? z : (expf(z) - 1.0f);
                hv[r] = (f16)z;
            }
            *(f16x4*)(vT + ((size_t)batch * D_ + e) * S_ + s) = hv;
        }
    }
}

// ===========================================================================
// k_scores: only upper-triangular tiles (kt >= qt). M = keys, N = queries.
// Epilogue: fp16 store (x C_SCALE) + fp32 ss accumulation -> ssbuf atomics.
// grid (36, B).
// ===========================================================================
__global__ __launch_bounds__(256)
void k_scores(const f16* __restrict__ xh, const int* __restrict__ etype,
              f16* __restrict__ sh, float* __restrict__ ssbuf)
{
    __shared__ __align__(16) char lds[16384];
    __shared__ float ssq[128];
    const int t = threadIdx.x;
    const int w = t >> 6, lane = t & 63, lr = lane & 15, quad = lane >> 4;
    const int wm = w & 1, wn = w >> 1;
    const int b = blockIdx.y;
    int ii = blockIdx.x, qt = 0;
    while (ii >= 8 - qt) { ii -= 8 - qt; ++qt; }
    const int kt = qt + ii;
    const int bk = kt * 128;   // keys (M)
    const int bq = qt * 128;   // queries (N)

    if (t < 128) ssq[t] = 0.0f;
    const f16* xb = xh + (size_t)b * S_ * D_;
    f32x4 acc[4][4] = {};
    gemm_core(xb + (size_t)bk * D_, D_, xb + (size_t)bq * D_, D_, D_,
              lds, t, wm, wn, lr, quad, acc);

    float ssl[4] = {};
#pragma unroll
    for (int i = 0; i < 4; ++i) {
        const int k4 = bk + wm * 64 + i * 16 + quad * 4;
        const int4 et = *(const int4*)(etype + b * S_ + k4);
        const int ev[4] = {et.x, et.y, et.z, et.w};
#pragma unroll
        for (int j = 0; j < 4; ++j) {
            const int q = bq + wn * 64 + j * 16 + lr;
            f16x4 hv;
#pragma unroll
            for (int r = 0; r < 4; ++r) {
                const bool keep = ((k4 + r) > q) || (ev[r] == 0);
                float sv = keep ? acc[i][j][r] * INV_TEMP : 0.0f;
                ssl[j] += sv * sv;
                hv[r] = (f16)(sv * C_SCALE);
            }
            *(f16x4*)(sh + ((size_t)b * S_ + q) * S_ + k4) = hv;
        }
    }
#pragma unroll
    for (int j = 0; j < 4; ++j) {
        float v = ssl[j];
        v += __shfl_xor(v, 16); v += __shfl_xor(v, 32);
        if (quad == 0) atomicAdd(&ssq[wn * 64 + j * 16 + lr], v);
    }
    __syncthreads();
    if (t < 128) atomicAdd(&ssbuf[b * S_ + bq + t], ssq[t]);
}

// ===========================================================================
// pad handling
// ===========================================================================
__global__ __launch_bounds__(256)
void k_padscan(const int* __restrict__ etype, int* __restrict__ padcnt,
               int* __restrict__ padpos)
{
    const int b = blockIdx.x, t = threadIdx.x;
    if (t == 0) padcnt[b] = 0;
    __syncthreads();
#pragma unroll
    for (int r = 0; r < 4; ++r) {
        const int k = t * 4 + r;
        if (etype[b * S_ + k] == 0) {
            const int s = atomicAdd(&padcnt[b], 1);
            if (s < NPMAX) padpos[b * NPMAX + s] = k;
        }
    }
}

// Coalesced: wave owns one q-row per iter; lane l covers x[q][8l..8l+8).
// grid (8, B): block covers 128 q rows (wave -> 32 rows).
__global__ __launch_bounds__(256)
void k_padstrip(const f16* __restrict__ xh, const int* __restrict__ padcnt,
                const int* __restrict__ padpos, float* __restrict__ padsc,
                float* __restrict__ ssbuf)
{
    const int b = blockIdx.y;
    const int np = min(padcnt[b], NPMAX);
    if (np == 0) return;
    const int t = threadIdx.x, wv = t >> 6, lane = t & 63;
    const f16* xb = xh + (size_t)b * S_ * D_;
    for (int sl = 0; sl < np; ++sl) {
        const int p = padpos[b * NPMAX + sl];
        const f16x8 xp = *(const f16x8*)(xb + (size_t)p * D_ + lane * 8);
        const int qlim = ((p >> 7) + 1) << 7;
        for (int i = 0; i < 32; ++i) {
            const int q = blockIdx.x * 128 + wv * 32 + i;
            const f16x8 a = *(const f16x8*)(xb + (size_t)q * D_ + lane * 8);
            float d = 0.0f;
#pragma unroll
            for (int r = 0; r < 8; ++r) d += (float)a[r] * (float)xp[r];
            d += __shfl_xor(d, 1);  d += __shfl_xor(d, 2);
            d += __shfl_xor(d, 4);  d += __shfl_xor(d, 8);
            d += __shfl_xor(d, 16); d += __shfl_xor(d, 32);
            if (lane == 0) {
                const float sp = d * INV_TEMP;
                padsc[((size_t)b * NPMAX + sl) * S_ + q] = sp * C_SCALE;
                if (q >= qlim) atomicAdd(&ssbuf[b * S_ + q], sp * sp);
            }
        }
    }
}

// ===========================================================================
// k_out: x_new = inv * (Sc @ v) + pad fixup. M = e (A=vT), N = q (B=sh).
// K-loop starts at the q-tile diagonal. inv computed inline from ssbuf.
// ===========================================================================
__global__ __launch_bounds__(256)
void k_out(const f16* __restrict__ vT, const f16* __restrict__ sh,
           const float* __restrict__ ssbuf, const int* __restrict__ padcnt,
           const int* __restrict__ padpos, const float* __restrict__ padsc,
           f16* __restrict__ xnext, float* __restrict__ out, const int accum)
{
    __shared__ __align__(16) char lds[16384];
    const int t = threadIdx.x;
    const int w = t >> 6, lane = t & 63, lr = lane & 15, quad = lane >> 4;
    const int wm = w & 1, wn = w >> 1;
    const int b = blockIdx.z;
    const int be = blockIdx.x * 128;
    const int bq = blockIdx.y * 128;
    f32x4 acc[4][4] = {};
    gemm_core(vT + ((size_t)b * D_ + be) * S_ + bq,
              S_, sh + ((size_t)b * S_ + bq) * S_ + bq, S_, S_ - bq,
              lds, t, wm, wn, lr, quad, acc);

    const int np = min(padcnt[b], NPMAX);
    for (int sl = 0; sl < np; ++sl) {
        const int p = padpos[b * NPMAX + sl];
        if (p >= bq) continue;
        float sp[4];
#pragma unroll
        for (int j = 0; j < 4; ++j)
            sp[j] = padsc[((size_t)b * NPMAX + sl) * S_ + bq + wn * 64 + j * 16 + lr];
#pragma unroll
        for (int i = 0; i < 4; ++i) {
#pragma unroll
            for (int r = 0; r < 4; ++r) {
                const int e = be + wm * 64 + i * 16 + quad * 4 + r;
                const float vv = (float)vT[((size_t)b * D_ + e) * S_ + p];
#pragma unroll
                for (int j = 0; j < 4; ++j) acc[i][j][r] += sp[j] * vv;
            }
        }
    }

#pragma unroll
    for (int j = 0; j < 4; ++j) {
        const int q = bq + wn * 64 + j * 16 + lr;
        const float inv = 1.0f / (C_SCALE * fmaxf(sqrtf(ssbuf[b * S_ + q]), 1e-5f));
#pragma unroll
        for (int i = 0; i < 4; ++i) {
            const int e4 = be + wm * 64 + i * 16 + quad * 4;
            const size_t o = ((size_t)b * S_ + q) * D_ + e4;
            f32x4 val;
            f16x4 hx;
#pragma unroll
            for (int r = 0; r < 4; ++r) {
                val[r] = acc[i][j][r] * inv;
                hx[r] = (f16)val[r];
            }
            if (accum) { const f32x4 old = *(const f32x4*)(out + o); val = val + old; }
            *(f32x4*)(out + o) = val;
            *(f16x4*)(xnext + o) = hx;
        }
    }
}

// ---------------------------------------------------------------------------
// Workspace (bytes):
//   X0 @0 (16M), X1 @16M, vT @32M, Wh @48M (2M),
//   ssbuf @50M (64K), padcnt @50M+128K (4K), padpos @50M+132K (4K),
//   padsc @51M (2M), sh @53M (32M)  -> 85M total
// ---------------------------------------------------------------------------
extern "C" void kernel_launch(void* const* d_in, const int* in_sizes, int n_in,
                              void* d_out, int out_size, void* d_ws, size_t ws_size,
                              hipStream_t stream) {
    const float* x0    = (const float*)d_in[0];
    const int*   etype = (const int*)d_in[2];
    const float* W     = (const float*)d_in[3];
    const float* bias  = (const float*)d_in[4];
    float* out = (float*)d_out;

    char* ws = (char*)d_ws;
    const size_t MB = 1u << 20;
    f16*   X0    = (f16*)(ws);
    f16*   X1    = (f16*)(ws + 16 * MB);
    f16*   vT    = (f16*)(ws + 32 * MB);
    f16*   Wh    = (f16*)(ws + 48 * MB);
    float* ssbuf = (float*)(ws + 50 * MB);
    int*   padcnt= (int*)(ws + 50 * MB + 131072);
    int*   padpos= (int*)(ws + 50 * MB + 135168);
    float* padsc = (float*)(ws + 51 * MB);
    f16*   sh    = (f16*)(ws + 53 * MB);

    k_conv<<<8192, 256, 0, stream>>>(x0, X0);
    k_conv<<<1024, 256, 0, stream>>>(W, Wh);
    k_padscan<<<B_, 256, 0, stream>>>(etype, padcnt, padpos);

    const dim3 gridV(128, 4);
    const dim3 gridS(36, B_);
    const dim3 gridP(8, B_);
    const dim3 gridO(4, 8, B_);
    for (int h = 0; h < H_; ++h) {
        f16* Xc = (h & 1) ? X1 : X0;
        f16* Xn = (h & 1) ? X0 : X1;
        k_gemm_v  <<<gridV, 256, 0, stream>>>(Xc, Wh + (size_t)h * D_ * D_,
                                              bias + (size_t)h * D_, vT, ssbuf);
        k_scores  <<<gridS, 256, 0, stream>>>(Xc, etype, sh, ssbuf);
        k_padstrip<<<gridP, 256, 0, stream>>>(Xc, padcnt, padpos, padsc, ssbuf);
        k_out     <<<gridO, 256, 0, stream>>>(vT, sh, ssbuf, padcnt, padpos, padsc,
                                              Xn, out, h > 0);
    }
}

// Round 7
// 457.937 us; speedup vs baseline: 1.6262x; 1.3909x over previous
//
#include <hip/hip_runtime.h>
#include <math.h>

#define B_ 16
#define S_ 1024
#define D_ 512
#define H_ 4
#define INV_TEMP 0.044194173824159216f   // 1/sqrt(512)
#define C_SCALE 0.00390625f              // 2^-8: keeps head-4 scores inside fp16 range
#define OUT_SCALE 256.0f

typedef _Float16 f16;
typedef _Float16 f16x8 __attribute__((ext_vector_type(8)));
typedef _Float16 f16x4 __attribute__((ext_vector_type(4)));
typedef float f32x4 __attribute__((ext_vector_type(4)));

#define AS1(p) ((const __attribute__((address_space(1))) void*)(p))
#define AS3(p) ((__attribute__((address_space(3))) void*)(p))
#define MFMA __builtin_amdgcn_mfma_f32_16x16x32_f16

// ---------------------------------------------------------------------------
// fp32 -> fp16 convert
// ---------------------------------------------------------------------------
__global__ __launch_bounds__(256)
void k_conv(const float* __restrict__ src, f16* __restrict__ dst)
{
    const int i = blockIdx.x * 256 + threadIdx.x;
    const float4 v = ((const float4*)src)[i];
    f16x4 h; h[0] = (f16)v.x; h[1] = (f16)v.y; h[2] = (f16)v.z; h[3] = (f16)v.w;
    ((f16x4*)dst)[i] = h;
}

// ---------------------------------------------------------------------------
// m97-style staging/MMA core (proven round 2)
// ---------------------------------------------------------------------------
__device__ __forceinline__ void stage128x32(const f16* __restrict__ src, int ld,
                                            char* lds0, int t)
{
    const f16* g0 = src + (size_t)(t >> 2) * ld + (t & 3) * 8;
    __builtin_amdgcn_global_load_lds(AS1(g0), AS3(lds0 + t * 16), 16, 0, 0);
    const f16* g1 = g0 + (size_t)64 * ld;
    __builtin_amdgcn_global_load_lds(AS1(g1), AS3(lds0 + 4096 + t * 16), 16, 0, 0);
}

__device__ __forceinline__ void mma_chunk(const char* ldsA, const char* ldsB,
                                          int wm, int wn, int lr, int quad,
                                          f32x4 (*acc)[4])
{
    f16x8 af[4], bf[4];
#pragma unroll
    for (int i = 0; i < 4; ++i)
        af[i] = *(const f16x8*)(ldsA + ((wm * 64 + i * 16 + lr) * 32 + quad * 8) * 2);
#pragma unroll
    for (int j = 0; j < 4; ++j)
        bf[j] = *(const f16x8*)(ldsB + ((wn * 64 + j * 16 + lr) * 32 + quad * 8) * 2);
#pragma unroll
    for (int i = 0; i < 4; ++i)
#pragma unroll
        for (int j = 0; j < 4; ++j)
            acc[i][j] = MFMA(af[i], bf[j], acc[i][j], 0, 0, 0);
}

__device__ __forceinline__ void gemm_core(const f16* A, int ldA, const f16* Bm, int ldB,
                                          int K, char* lds, int t, int wm, int wn,
                                          int lr, int quad, f32x4 (*acc)[4])
{
    for (int k0 = 0; k0 < K; k0 += 32) {
        stage128x32(A + k0, ldA, lds, t);
        stage128x32(Bm + k0, ldB, lds + 8192, t);
        __syncthreads();
        mma_chunk(lds, lds + 8192, wm, wn, lr, quad, acc);
        __syncthreads();
    }
}

// ===========================================================================
// vT = ELU(x @ W^T + b)^T  stored [B][D][S] fp16  (exact round-2 version;
// x-tiles already XCD-local: block ids bx+128k = bx mod 8)
// ===========================================================================
__global__ __launch_bounds__(256)
void k_gemm_v(const f16* __restrict__ xh, const f16* __restrict__ Wh,
              const float* __restrict__ bias, f16* __restrict__ vT)
{
    __shared__ __align__(16) char lds[16384];
    const int t = threadIdx.x;
    const int w = t >> 6, lane = t & 63, lr = lane & 15, quad = lane >> 4;
    const int wm = w & 1, wn = w >> 1;
    const int bm = blockIdx.x * 128;
    const int bn = blockIdx.y * 128;
    f32x4 acc[4][4] = {};
    gemm_core(xh + (size_t)bm * D_, D_, Wh + (size_t)bn * D_, D_, D_,
              lds, t, wm, wn, lr, quad, acc);
#pragma unroll
    for (int j = 0; j < 4; ++j) {
        const int e = bn + wn * 64 + j * 16 + lr;
        const float be = bias[e];
#pragma unroll
        for (int i = 0; i < 4; ++i) {
            const int m = bm + wm * 64 + i * 16 + quad * 4;
            const int batch = m >> 10, s = m & 1023;
            f16x4 hv;
#pragma unroll
            for (int r = 0; r < 4; ++r) {
                float z = acc[i][j][r] + be;
                z = (z > 0.0f) ? z : (expf(z) - 1.0f);
                hv[r] = (f16)z;
            }
            *(f16x4*)(vT + ((size_t)batch * D_ + e) * S_ + s) = hv;
        }
    }
}

// ===========================================================================
// k_scores (round-2 math, XCD-pinned mapping): 1024 blocks, 1-D.
//   xcd = i&7 owns batches {2*xcd, 2*xcd+1}; 64 tiles per batch.
// ===========================================================================
__global__ __launch_bounds__(256)
void k_scores(const f16* __restrict__ xh, const int* __restrict__ etype,
              f16* __restrict__ sh)
{
    __shared__ __align__(16) char lds[16384];
    const int t = threadIdx.x;
    const int w = t >> 6, lane = t & 63, lr = lane & 15, quad = lane >> 4;
    const int wm = w & 1, wn = w >> 1;
    const int i0 = blockIdx.x;
    const int xcd = i0 & 7, j0 = i0 >> 3;          // j0 in [0,128)
    const int b = 2 * xcd + (j0 & 1);
    const int tile = j0 >> 1;                      // [0,64)
    const int bk = (tile & 7) * 128;               // keys (M)
    const int bq = (tile >> 3) * 128;              // queries (N)

    const f16* xb = xh + (size_t)b * S_ * D_;
    f32x4 acc[4][4] = {};
    gemm_core(xb + (size_t)bk * D_, D_, xb + (size_t)bq * D_, D_, D_,
              lds, t, wm, wn, lr, quad, acc);
    const float sc = INV_TEMP * C_SCALE;
#pragma unroll
    for (int i = 0; i < 4; ++i) {
        const int k4 = bk + wm * 64 + i * 16 + quad * 4;
        const int4 et = *(const int4*)(etype + b * S_ + k4);
        const int ev[4] = {et.x, et.y, et.z, et.w};
#pragma unroll
        for (int j = 0; j < 4; ++j) {
            const int q = bq + wn * 64 + j * 16 + lr;
            f16x4 hv;
#pragma unroll
            for (int r = 0; r < 4; ++r) {
                const bool keep = ((k4 + r) > q) || (ev[r] == 0);
                hv[r] = (f16)(keep ? acc[i][j][r] * sc : 0.0f);
            }
            *(f16x4*)(sh + ((size_t)b * S_ + q) * S_ + k4) = hv;
        }
    }
}

// ===========================================================================
// k_rownorm (round-2 math, XCD-pinned): 4096 blocks, 4 rows/block (1/wave)
// ===========================================================================
__global__ __launch_bounds__(256)
void k_rownorm(const f16* __restrict__ sh, float* __restrict__ inv)
{
    const int w = threadIdx.x >> 6, lane = threadIdx.x & 63;
    const int i0 = blockIdx.x;
    const int xcd = i0 & 7, j0 = i0 >> 3;          // j0 in [0,512)
    const int b = 2 * xcd + (j0 & 1);
    const int row = b * S_ + (j0 >> 1) * 4 + w;
    const f16* p = sh + (size_t)row * S_;
    const f16x8 a = *(const f16x8*)(p + lane * 8);
    const f16x8 c = *(const f16x8*)(p + 512 + lane * 8);
    float ss = 0.0f;
#pragma unroll
    for (int r = 0; r < 8; ++r) {
        const float x = (float)a[r]; ss += x * x;
        const float y = (float)c[r]; ss += y * y;
    }
#pragma unroll
    for (int off = 32; off; off >>= 1) ss += __shfl_down(ss, off, 64);
    if (lane == 0) {
        const float norm_true = sqrtf(ss) * OUT_SCALE;   // undo C_SCALE
        inv[row] = 1.0f / (C_SCALE * fmaxf(norm_true, 1e-5f));
    }
}

// ===========================================================================
// k_out (round-2 math, XCD-pinned): 512 blocks, 1-D.
//   Within an XCD, tiles iterate e fastest -> 4 e-blocks of same (q,b) are
//   temporally adjacent on the same XCD -> sh slab fetched once into L2.
// ===========================================================================
__global__ __launch_bounds__(256)
void k_out(const f16* __restrict__ vT, const f16* __restrict__ sh,
           const float* __restrict__ inv, f16* __restrict__ xh,
           float* __restrict__ out, const int accum)
{
    __shared__ __align__(16) char lds[16384];
    const int t = threadIdx.x;
    const int w = t >> 6, lane = t & 63, lr = lane & 15, quad = lane >> 4;
    const int wm = w & 1, wn = w >> 1;
    const int i0 = blockIdx.x;
    const int xcd = i0 & 7, j0 = i0 >> 3;          // j0 in [0,64)
    const int b = 2 * xcd + (j0 & 1);
    const int tile = j0 >> 1;                      // [0,32)
    const int be = (tile & 3) * 128;               // e (M), fastest
    const int bq = (tile >> 2) * 128;              // q (N)
    f32x4 acc[4][4] = {};
    gemm_core(vT + ((size_t)b * D_ + be) * S_, S_,
              sh + ((size_t)b * S_ + bq) * S_, S_, S_,
              lds, t, wm, wn, lr, quad, acc);
#pragma unroll
    for (int j = 0; j < 4; ++j) {
        const int q = bq + wn * 64 + j * 16 + lr;
        const float scl = inv[b * S_ + q];
#pragma unroll
        for (int i = 0; i < 4; ++i) {
            const int e4 = be + wm * 64 + i * 16 + quad * 4;
            const size_t o = ((size_t)b * S_ + q) * D_ + e4;
            f32x4 xnew;
            f16x4 hx;
#pragma unroll
            for (int r = 0; r < 4; ++r) {
                xnew[r] = acc[i][j][r] * scl;
                hx[r] = (f16)xnew[r];
            }
            f32x4 val = xnew;
            if (accum) { const f32x4 old = *(const f32x4*)(out + o); val = val + old; }
            *(f32x4*)(out + o) = val;
            *(f16x4*)(xh + o) = hx;
        }
    }
}

// ---------------------------------------------------------------------------
// Workspace: xh @0 (16M), vT @16M (16M), sh @32M (32M), Wh @64M (2M),
//            inv @66M (64K)
// ---------------------------------------------------------------------------
extern "C" void kernel_launch(void* const* d_in, const int* in_sizes, int n_in,
                              void* d_out, int out_size, void* d_ws, size_t ws_size,
                              hipStream_t stream) {
    const float* x0    = (const float*)d_in[0];
    const int*   etype = (const int*)d_in[2];
    const float* W     = (const float*)d_in[3];
    const float* bias  = (const float*)d_in[4];
    float* out = (float*)d_out;

    char* ws = (char*)d_ws;
    f16*   xh  = (f16*)(ws);
    f16*   vT  = (f16*)(ws + (16u << 20));
    f16*   sh  = (f16*)(ws + (32u << 20));
    f16*   Wh  = (f16*)(ws + (64u << 20));
    float* inv = (float*)(ws + (66u << 20));

    k_conv<<<8192, 256, 0, stream>>>(x0, xh);
    k_conv<<<1024, 256, 0, stream>>>(W, Wh);

    const dim3 gridV(128, 4);
    for (int h = 0; h < H_; ++h) {
        k_gemm_v <<<gridV, 256, 0, stream>>>(xh, Wh + (size_t)h * D_ * D_,
                                             bias + (size_t)h * D_, vT);
        k_scores <<<1024, 256, 0, stream>>>(xh, etype, sh);
        k_rownorm<<<4096, 256, 0, stream>>>(sh, inv);
        k_out    <<<512, 256, 0, stream>>>(vT, sh, inv, xh, out, h > 0);
    }
}